// Round 10
// baseline (200.980 us; speedup 1.0000x reference)
//
#include <hip/hip_runtime.h>
#include <stdint.h>

#define D_MODEL 1024
#define NHEAD 16
#define HD 64
#define BB 2
#define TT 2048
#define MR (BB*TT)   // 4096 rows

typedef unsigned short u16;
typedef __bf16 bf16x8 __attribute__((ext_vector_type(8)));
typedef u16 u16x8 __attribute__((ext_vector_type(8)));
typedef float f32x4 __attribute__((ext_vector_type(4)));

__device__ __forceinline__ u16 f2bf(float f) {
  union { float f; unsigned u; } v; v.f = f;
  unsigned r = v.u + 0x7FFFu + ((v.u >> 16) & 1u);
  return (u16)(r >> 16);
}
__device__ __forceinline__ unsigned pack2bf(float a, float b) {
  return (unsigned)f2bf(a) | ((unsigned)f2bf(b) << 16);
}

__device__ __forceinline__ void gload_lds16(const void* g, void* l) {
  __builtin_amdgcn_global_load_lds(
      (const __attribute__((address_space(1))) void*)g,
      (__attribute__((address_space(3))) void*)l, 16, 0, 0);
}

// ---------------- f32 -> bf16 convert (vectorized) ----------------
__global__ void k_f32_to_bf16(const float* __restrict__ src, u16* __restrict__ dst, int n4) {
  int idx = blockIdx.x * blockDim.x + threadIdx.x;
  int stride = gridDim.x * blockDim.x;
  for (int i = idx; i < n4; i += stride) {
    float4 v = reinterpret_cast<const float4*>(src)[i];
    ushort4 o;
    o.x = f2bf(v.x); o.y = f2bf(v.y); o.z = f2bf(v.z); o.w = f2bf(v.w);
    reinterpret_cast<ushort4*>(dst)[i] = o;
  }
}

// ---------------- transpose f32 [K][N] -> bf16 [N][K], both weights fused ----------------
__global__ void k_transpose_both(const float* __restrict__ wqkv, const float* __restrict__ wout,
                                 u16* __restrict__ dqkv, u16* __restrict__ dout) {
  __shared__ float tile[32][33];
  int bx = blockIdx.x;
  const float* src; u16* dst; int N; int n0;
  if (bx < 96) { src = wqkv; dst = dqkv; N = 3 * D_MODEL; n0 = bx * 32; }
  else         { src = wout; dst = dout; N = D_MODEL;     n0 = (bx - 96) * 32; }
  const int K = D_MODEL;
  int k0 = blockIdx.y * 32;
  int tx = threadIdx.x, ty = threadIdx.y;  // block (32,8)
  #pragma unroll
  for (int i = 0; i < 32; i += 8)
    tile[ty + i][tx] = src[(size_t)(k0 + ty + i) * N + n0 + tx];
  __syncthreads();
  #pragma unroll
  for (int i = 0; i < 32; i += 8)
    dst[(size_t)(n0 + ty + i) * K + k0 + tx] = f2bf(tile[tx][ty + i]);
}

// ---------------- bf16 GEMM, B^T input, 128x128 tile ----------------
// MODE 0: qkv projection -> scatter Q/K into [B][H][T][64], V into [B][H][64][T] (transposed), +bias
// MODE 1: out = A @ B + bias, f32 row-major
template<int MODE>
__global__ __launch_bounds__(256)
void k_gemm_bt(const u16* __restrict__ A, const u16* __restrict__ Bt,
               const float* __restrict__ bias,
               u16* __restrict__ q_out, u16* __restrict__ k_out, u16* __restrict__ v_out,
               float* __restrict__ c_out, int M, int N, int K)
{
  __shared__ __align__(16) u16 a_sh[128 * 64];
  __shared__ __align__(16) u16 b_sh[128 * 64];
  const int u = threadIdx.x;
  const int lane = u & 63;
  const int w = u >> 6;
  const int wr = w >> 1, wc = w & 1;
  const int m0 = blockIdx.y * 128;
  const int n0 = blockIdx.x * 128;
  const int r = lane & 15, q4 = lane >> 4;

  f32x4 acc[4][4];
  #pragma unroll
  for (int i = 0; i < 4; i++)
    #pragma unroll
    for (int j = 0; j < 4; j++) acc[i][j] = {0.f, 0.f, 0.f, 0.f};

  const int arow = u >> 3;        // 0..31
  const int acol = (u & 7) * 8;   // 0..56
  const u16* Ag = A + (size_t)(m0 + arow) * K + acol;
  const u16* Bg = Bt + (size_t)(n0 + arow) * K + acol;

  for (int k0 = 0; k0 < K; k0 += 64) {
    #pragma unroll
    for (int i = 0; i < 4; i++) {
      gload_lds16(Ag + (size_t)i * 32 * K + k0, &a_sh[(i * 32 + w * 8) * 64]);
      gload_lds16(Bg + (size_t)i * 32 * K + k0, &b_sh[(i * 32 + w * 8) * 64]);
    }
    __syncthreads();
    #pragma unroll
    for (int kc = 0; kc < 2; kc++) {
      bf16x8 af[4], bfr[4];
      #pragma unroll
      for (int m = 0; m < 4; m++)
        af[m] = *reinterpret_cast<const bf16x8*>(&a_sh[(wr * 64 + m * 16 + r) * 64 + kc * 32 + q4 * 8]);
      #pragma unroll
      for (int n = 0; n < 4; n++)
        bfr[n] = *reinterpret_cast<const bf16x8*>(&b_sh[(wc * 64 + n * 16 + r) * 64 + kc * 32 + q4 * 8]);
      #pragma unroll
      for (int m = 0; m < 4; m++)
        #pragma unroll
        for (int n = 0; n < 4; n++)
          acc[m][n] = __builtin_amdgcn_mfma_f32_16x16x32_bf16(af[m], bfr[n], acc[m][n], 0, 0, 0);
    }
    __syncthreads();
  }

  if (MODE == 0) {
    #pragma unroll
    for (int n = 0; n < 4; n++) {
      int gcol = n0 + wc * 64 + n * 16 + r;
      int which = gcol >> 10;   // uniform within fragment (16-aligned ranges)
      int rem = gcol & 1023;
      int h = rem >> 6, d = rem & 63;
      float bv = bias[gcol];
      #pragma unroll
      for (int m = 0; m < 4; m++) {
        #pragma unroll
        for (int reg = 0; reg < 4; reg++) {
          int grow = m0 + wr * 64 + m * 16 + q4 * 4 + reg;
          int b = grow >> 11, t = grow & 2047;
          u16 val = f2bf(acc[m][n][reg] + bv);
          if (which == 0)
            q_out[(((size_t)(b * NHEAD + h) * TT + t) << 6) + d] = val;
          else if (which == 1)
            k_out[(((size_t)(b * NHEAD + h) * TT + t) << 6) + d] = val;
          else  // V transposed: [b][h][d][t]
            v_out[(((size_t)(b * NHEAD + h) * HD + d) * TT) + t] = val;
        }
      }
    }
  } else {
    #pragma unroll
    for (int m = 0; m < 4; m++) {
      #pragma unroll
      for (int reg = 0; reg < 4; reg++) {
        int grow = m0 + wr * 64 + m * 16 + q4 * 4 + reg;
        #pragma unroll
        for (int n = 0; n < 4; n++) {
          int gcol = n0 + wc * 64 + n * 16 + r;
          c_out[(size_t)grow * N + gcol] = acc[m][n][reg] + bias[gcol];
        }
      }
    }
  }
}

// ---------------- causal flash attention, split-K, equal-length waves ----------------
// 1024 blocks of 256 (4 waves), 4 blocks/CU -- whole grid resident. Block
// handles the q-tile PAIR (2t, 2t+1) which share c = t+1 k-tiles; waves
// (t4,hf) = (w>>1, w&1) each process one k-half of one tile -> all 4 waves
// have ~equal work and retire together (R9's {0,16,1,16} imbalance fix).
// Blocks dispatched longest-first (t = 31-jj). Natural VGPR (~112) = the
// 4-waves/SIMD rung; NO launch_bounds min-waves arg (R7/R8 spill bug).
#define SCL2 0.18033688011112042f   // 0.125 * log2(e)

__device__ __forceinline__ void attn_tile(
    const u16* __restrict__ Kp, const u16* __restrict__ Vp,
    const bf16x8 (&kin)[8], bf16x8 (&kout)[8],
    const bf16x8 (&qf)[2][2], f32x4 (&of)[2][4],
    float (&m_run)[2], float (&lp)[2],
    u16* pw, int kt, bool diag, int q0, int r, int q4)
{
  // 1) prefetch next K tile into kout (overfetch past range end is harmless)
  {
    const u16* kp = Kp + (size_t)(kt + 1) * (64 * HD);
    #pragma unroll
    for (int n = 0; n < 4; n++) {
      kout[n * 2 + 0] = *reinterpret_cast<const bf16x8*>(kp + n * 1024);
      kout[n * 2 + 1] = *reinterpret_cast<const bf16x8*>(kp + n * 1024 + 32);
    }
  }

  // 2) S^T = mfma(K, Q): sf[g][n][reg] = S[k][q], lane's q = q0+g*16+r
  f32x4 sf[2][4];
  __builtin_amdgcn_s_setprio(1);
  #pragma unroll
  for (int g = 0; g < 2; g++)
    #pragma unroll
    for (int n = 0; n < 4; n++) {
      f32x4 a = {0.f, 0.f, 0.f, 0.f};
      a = __builtin_amdgcn_mfma_f32_16x16x32_bf16(kin[n * 2 + 0], qf[g][0], a, 0, 0, 0);
      a = __builtin_amdgcn_mfma_f32_16x16x32_bf16(kin[n * 2 + 1], qf[g][1], a, 0, 0, 0);
      sf[g][n] = a;
    }
  __builtin_amdgcn_s_setprio(0);

  // 3) V fragments for this tile (latency hides under softmax)
  bf16x8 vf[2][4];
  #pragma unroll
  for (int d0 = 0; d0 < 4; d0++) {
    const u16* vp = Vp + (size_t)d0 * (16 * TT) + kt * 64;
    vf[0][d0] = *reinterpret_cast<const bf16x8*>(vp);
    vf[1][d0] = *reinterpret_cast<const bf16x8*>(vp + 32);
  }

  // 4) per-group in-lane online softmax
  #pragma unroll
  for (int g = 0; g < 2; g++) {
    const int myq = q0 + g * 16 + r;
    #pragma unroll
    for (int n = 0; n < 4; n++)
      #pragma unroll
      for (int reg = 0; reg < 4; reg++) {
        float s = sf[g][n][reg] * SCL2;
        if (diag) {
          int kg = kt * 64 + n * 16 + q4 * 4 + reg;
          if (kg > myq) s = -1e30f;
        }
        sf[g][n][reg] = s;
      }
    float a0 = fmaxf(fmaxf(sf[g][0][0], sf[g][0][1]), fmaxf(sf[g][0][2], sf[g][0][3]));
    float a1 = fmaxf(fmaxf(sf[g][1][0], sf[g][1][1]), fmaxf(sf[g][1][2], sf[g][1][3]));
    float a2 = fmaxf(fmaxf(sf[g][2][0], sf[g][2][1]), fmaxf(sf[g][2][2], sf[g][2][3]));
    float a3 = fmaxf(fmaxf(sf[g][3][0], sf[g][3][1]), fmaxf(sf[g][3][2], sf[g][3][3]));
    float mt = fmaxf(fmaxf(a0, a1), fmaxf(a2, a3));
    mt = fmaxf(mt, __shfl_xor(mt, 16));
    mt = fmaxf(mt, __shfl_xor(mt, 32));
    float mnew = fmaxf(m_run[g], mt);
    float alpha = __builtin_amdgcn_exp2f(m_run[g] - mnew);
    m_run[g] = mnew;

    f32x4 ss = {0.f, 0.f, 0.f, 0.f};
    #pragma unroll
    for (int n = 0; n < 4; n++) {
      #pragma unroll
      for (int reg = 0; reg < 4; reg++)
        sf[g][n][reg] = __builtin_amdgcn_exp2f(sf[g][n][reg] - mnew);
      ss += sf[g][n];
    }
    lp[g] = lp[g] * alpha + ((ss[0] + ss[1]) + (ss[2] + ss[3]));

    #pragma unroll
    for (int d0 = 0; d0 < 4; d0++)
      #pragma unroll
      for (int reg = 0; reg < 4; reg++)
        of[g][d0][reg] *= alpha;

    // P -> per-wave LDS [q][k] (packed 8B writes; no barrier needed)
    #pragma unroll
    for (int n = 0; n < 4; n++) {
      uint2 pk;
      pk.x = pack2bf(sf[g][n][0], sf[g][n][1]);
      pk.y = pack2bf(sf[g][n][2], sf[g][n][3]);
      *reinterpret_cast<uint2*>(&pw[(g * 16 + r) * 72 + n * 16 + q4 * 4]) = pk;
    }
  }

  // 5) O^T += mfma(V, P)
  #pragma unroll
  for (int g = 0; g < 2; g++)
    #pragma unroll
    for (int kc = 0; kc < 2; kc++) {
      bf16x8 pa = *reinterpret_cast<const bf16x8*>(&pw[(g * 16 + r) * 72 + kc * 32 + q4 * 8]);
      #pragma unroll
      for (int d0 = 0; d0 < 4; d0++)
        of[g][d0] = __builtin_amdgcn_mfma_f32_16x16x32_bf16(vf[kc][d0], pa, of[g][d0], 0, 0, 0);
    }
}

__global__ __launch_bounds__(256)
void k_attn(const u16* __restrict__ Q, const u16* __restrict__ Kk,
            const u16* __restrict__ Vt, u16* __restrict__ Y)
{
  __shared__ __align__(16) u16 p_sh[4][32 * 72];   // 18432 B; reused as merge buffer

  const int u = threadIdx.x;
  const int lane = u & 63;
  const int w = u >> 6;                 // 0..3
  const int r = lane & 15, q4 = lane >> 4;
  // XCD-resident head map: all 32 blocks of a head share blockIdx&7
  const int xcd = blockIdx.x & 7;
  const int j = blockIdx.x >> 3;        // 0..127
  const int bh = xcd * 4 + (j >> 5);    // 0..31
  const int jj = j & 31;                // 0..31
  const int t = 31 - jj;                // longest-first dispatch
  const int t4 = w >> 1;                // tile-in-pair 0/1
  const int hf = w & 1;                 // k-half 0/1
  const int wt = 2 * t + t4;            // q-tile 0..63; pair shares c = t+1
  const int b = bh >> 4, h = bh & 15;
  const size_t head_off = (size_t)bh * TT * HD;   // Q,K: [t][d];  Vt: [d][t]
  const int q0 = wt * 32;
  const int c = (wt >> 1) + 1;          // total 64-col k-tiles for this q-tile
  const int kt0 = hf ? (c >> 1) : 0;
  const int kte = hf ? c : (c >> 1);

  const u16* Kp = Kk + head_off + (size_t)r * HD + q4 * 8;
  const u16* Vp = Vt + head_off + (size_t)r * TT + q4 * 8;

  bf16x8 qf[2][2];
  #pragma unroll
  for (int g = 0; g < 2; g++) {
    const u16* qp = &Q[head_off + (size_t)(q0 + g * 16 + r) * HD + q4 * 8];
    qf[g][0] = *reinterpret_cast<const bf16x8*>(qp);
    qf[g][1] = *reinterpret_cast<const bf16x8*>(qp + 32);
  }

  f32x4 of[2][4];
  #pragma unroll
  for (int g = 0; g < 2; g++)
    #pragma unroll
    for (int k = 0; k < 4; k++) of[g][k] = {0.f, 0.f, 0.f, 0.f};
  float m_run[2] = {-1e30f, -1e30f};
  float lp[2] = {0.f, 0.f};

  u16* pw = &p_sh[w][0];

  // prologue: load K tile kt0 into kfA (harmless read even if range empty)
  bf16x8 kfA[8], kfB[8];
  {
    const u16* kp = Kp + (size_t)kt0 * (64 * HD);
    #pragma unroll
    for (int n = 0; n < 4; n++) {
      kfA[n * 2 + 0] = *reinterpret_cast<const bf16x8*>(kp + n * 1024);
      kfA[n * 2 + 1] = *reinterpret_cast<const bf16x8*>(kp + n * 1024 + 32);
    }
  }

  for (int kt = kt0; kt < kte; kt += 2) {
    attn_tile(Kp, Vp, kfA, kfB, qf, of, m_run, lp, pw, kt, kt == c - 1, q0, r, q4);
    if (kt + 1 < kte)
      attn_tile(Kp, Vp, kfB, kfA, qf, of, m_run, lp, pw, kt + 1, kt + 1 == c - 1, q0, r, q4);
  }

  // ---- split-K merge via LDS (reuse p_sh; per-tile region indexed by t4) ----
  // per-lane layout (36 floats): [of g0: 16][of g1: 16][m0,l0,m1,l1]
  float* mb = reinterpret_cast<float*>(&p_sh[0][0]) + (size_t)t4 * 2304 + lane * 36;
  __syncthreads();                        // everyone done reading their P tile
  if (hf == 0) {
    #pragma unroll
    for (int g = 0; g < 2; g++) {
      #pragma unroll
      for (int d0 = 0; d0 < 4; d0++)
        *reinterpret_cast<f32x4*>(&mb[g * 16 + d0 * 4]) = of[g][d0];
      mb[32 + g * 2 + 0] = m_run[g];
      mb[32 + g * 2 + 1] = lp[g];
    }
  }
  __syncthreads();
  if (hf == 1) {
    #pragma unroll
    for (int g = 0; g < 2; g++) {
      float m0 = mb[32 + g * 2 + 0], l0 = mb[32 + g * 2 + 1];
      float M = fmaxf(m0, m_run[g]);
      float a0 = __builtin_amdgcn_exp2f(m0 - M);
      float a1 = __builtin_amdgcn_exp2f(m_run[g] - M);
      float l = l0 * a0 + lp[g] * a1;
      l += __shfl_xor(l, 16);
      l += __shfl_xor(l, 32);
      float inv = 1.0f / l;
      const int t2 = q0 + g * 16 + r;
      #pragma unroll
      for (int d0 = 0; d0 < 4; d0++) {
        f32x4 o0 = *reinterpret_cast<f32x4*>(&mb[g * 16 + d0 * 4]);
        f32x4 oc = o0 * a0 + of[g][d0] * a1;
        uint2 pk;
        pk.x = pack2bf(oc[0] * inv, oc[1] * inv);
        pk.y = pack2bf(oc[2] * inv, oc[3] * inv);
        *reinterpret_cast<uint2*>(&Y[((size_t)(b * TT + t2) << 10) + h * 64 + d0 * 16 + q4 * 4]) = pk;
      }
    }
  }
}

// ---------------- host launcher ----------------
extern "C" void kernel_launch(void* const* d_in, const int* in_sizes, int n_in,
                              void* d_out, int out_size, void* d_ws, size_t ws_size,
                              hipStream_t stream) {
  const float* x     = (const float*)d_in[0];
  const float* w_qkv = (const float*)d_in[1];
  const float* b_qkv = (const float*)d_in[2];
  const float* w_out = (const float*)d_in[3];
  const float* b_out = (const float*)d_in[4];
  float* out = (float*)d_out;

  uint8_t* ws = (uint8_t*)d_ws;
  u16* xb    = (u16*)(ws);                    // 8 MB  (reused as y_heads later)
  u16* wqkvT = (u16*)(ws + (8u  << 20));      // 6 MB
  u16* woutT = (u16*)(ws + (14u << 20));      // 2 MB
  u16* Qh    = (u16*)(ws + (16u << 20));      // 8 MB
  u16* Kh    = (u16*)(ws + (24u << 20));      // 8 MB
  u16* Vth   = (u16*)(ws + (32u << 20));      // 8 MB  (transposed V; also absorbs K prefetch overfetch)

  k_f32_to_bf16<<<1024, 256, 0, stream>>>(x, xb, (MR * D_MODEL) / 4);
  k_transpose_both<<<dim3(128, D_MODEL / 32), dim3(32, 8), 0, stream>>>(
      w_qkv, w_out, wqkvT, woutT);

  k_gemm_bt<0><<<dim3(3 * D_MODEL / 128, MR / 128), 256, 0, stream>>>(
      xb, wqkvT, b_qkv, Qh, Kh, Vth, nullptr, MR, 3 * D_MODEL, D_MODEL);

  u16* Yh = xb;  // reuse x-bf16 region
  k_attn<<<dim3(1024), dim3(256), 0, stream>>>(Qh, Kh, Vth, Yh);

  k_gemm_bt<1><<<dim3(D_MODEL / 128, MR / 128), 256, 0, stream>>>(
      Yh, woutT, b_out, nullptr, nullptr, nullptr, out, MR, D_MODEL, D_MODEL);
}

// Round 11
// 185.993 us; speedup vs baseline: 1.0806x; 1.0806x over previous
//
#include <hip/hip_runtime.h>
#include <stdint.h>

#define D_MODEL 1024
#define NHEAD 16
#define HD 64
#define BB 2
#define TT 2048
#define MR (BB*TT)   // 4096 rows

typedef unsigned short u16;
typedef __bf16 bf16x8 __attribute__((ext_vector_type(8)));
typedef u16 u16x8 __attribute__((ext_vector_type(8)));
typedef float f32x4 __attribute__((ext_vector_type(4)));

__device__ __forceinline__ u16 f2bf(float f) {
  union { float f; unsigned u; } v; v.f = f;
  unsigned r = v.u + 0x7FFFu + ((v.u >> 16) & 1u);
  return (u16)(r >> 16);
}
__device__ __forceinline__ unsigned pack2bf(float a, float b) {
  return (unsigned)f2bf(a) | ((unsigned)f2bf(b) << 16);
}

__device__ __forceinline__ void gload_lds16(const void* g, void* l) {
  __builtin_amdgcn_global_load_lds(
      (const __attribute__((address_space(1))) void*)g,
      (__attribute__((address_space(3))) void*)l, 16, 0, 0);
}

// ---------------- f32 -> bf16 convert (vectorized) ----------------
__global__ void k_f32_to_bf16(const float* __restrict__ src, u16* __restrict__ dst, int n4) {
  int idx = blockIdx.x * blockDim.x + threadIdx.x;
  int stride = gridDim.x * blockDim.x;
  for (int i = idx; i < n4; i += stride) {
    float4 v = reinterpret_cast<const float4*>(src)[i];
    ushort4 o;
    o.x = f2bf(v.x); o.y = f2bf(v.y); o.z = f2bf(v.z); o.w = f2bf(v.w);
    reinterpret_cast<ushort4*>(dst)[i] = o;
  }
}

// ---------------- transpose f32 [K][N] -> bf16 [N][K], both weights fused ----------------
__global__ void k_transpose_both(const float* __restrict__ wqkv, const float* __restrict__ wout,
                                 u16* __restrict__ dqkv, u16* __restrict__ dout) {
  __shared__ float tile[32][33];
  int bx = blockIdx.x;
  const float* src; u16* dst; int N; int n0;
  if (bx < 96) { src = wqkv; dst = dqkv; N = 3 * D_MODEL; n0 = bx * 32; }
  else         { src = wout; dst = dout; N = D_MODEL;     n0 = (bx - 96) * 32; }
  const int K = D_MODEL;
  int k0 = blockIdx.y * 32;
  int tx = threadIdx.x, ty = threadIdx.y;  // block (32,8)
  #pragma unroll
  for (int i = 0; i < 32; i += 8)
    tile[ty + i][tx] = src[(size_t)(k0 + ty + i) * N + n0 + tx];
  __syncthreads();
  #pragma unroll
  for (int i = 0; i < 32; i += 8)
    dst[(size_t)(n0 + ty + i) * K + k0 + tx] = f2bf(tile[tx][ty + i]);
}

// ---------------- bf16 GEMM, B^T input, 128x128 tile ----------------
// MODE 0: qkv projection -> scatter Q/K into [B][H][T][64], V into [B][H][64][T] (transposed), +bias
// MODE 1: out = A @ B + bias, f32 row-major
template<int MODE>
__global__ __launch_bounds__(256)
void k_gemm_bt(const u16* __restrict__ A, const u16* __restrict__ Bt,
               const float* __restrict__ bias,
               u16* __restrict__ q_out, u16* __restrict__ k_out, u16* __restrict__ v_out,
               float* __restrict__ c_out, int M, int N, int K)
{
  __shared__ __align__(16) u16 a_sh[128 * 64];
  __shared__ __align__(16) u16 b_sh[128 * 64];
  const int u = threadIdx.x;
  const int lane = u & 63;
  const int w = u >> 6;
  const int wr = w >> 1, wc = w & 1;
  const int m0 = blockIdx.y * 128;
  const int n0 = blockIdx.x * 128;
  const int r = lane & 15, q4 = lane >> 4;

  f32x4 acc[4][4];
  #pragma unroll
  for (int i = 0; i < 4; i++)
    #pragma unroll
    for (int j = 0; j < 4; j++) acc[i][j] = {0.f, 0.f, 0.f, 0.f};

  const int arow = u >> 3;        // 0..31
  const int acol = (u & 7) * 8;   // 0..56
  const u16* Ag = A + (size_t)(m0 + arow) * K + acol;
  const u16* Bg = Bt + (size_t)(n0 + arow) * K + acol;

  for (int k0 = 0; k0 < K; k0 += 64) {
    #pragma unroll
    for (int i = 0; i < 4; i++) {
      gload_lds16(Ag + (size_t)i * 32 * K + k0, &a_sh[(i * 32 + w * 8) * 64]);
      gload_lds16(Bg + (size_t)i * 32 * K + k0, &b_sh[(i * 32 + w * 8) * 64]);
    }
    __syncthreads();
    #pragma unroll
    for (int kc = 0; kc < 2; kc++) {
      bf16x8 af[4], bfr[4];
      #pragma unroll
      for (int m = 0; m < 4; m++)
        af[m] = *reinterpret_cast<const bf16x8*>(&a_sh[(wr * 64 + m * 16 + r) * 64 + kc * 32 + q4 * 8]);
      #pragma unroll
      for (int n = 0; n < 4; n++)
        bfr[n] = *reinterpret_cast<const bf16x8*>(&b_sh[(wc * 64 + n * 16 + r) * 64 + kc * 32 + q4 * 8]);
      #pragma unroll
      for (int m = 0; m < 4; m++)
        #pragma unroll
        for (int n = 0; n < 4; n++)
          acc[m][n] = __builtin_amdgcn_mfma_f32_16x16x32_bf16(af[m], bfr[n], acc[m][n], 0, 0, 0);
    }
    __syncthreads();
  }

  if (MODE == 0) {
    #pragma unroll
    for (int n = 0; n < 4; n++) {
      int gcol = n0 + wc * 64 + n * 16 + r;
      int which = gcol >> 10;   // uniform within fragment (16-aligned ranges)
      int rem = gcol & 1023;
      int h = rem >> 6, d = rem & 63;
      float bv = bias[gcol];
      #pragma unroll
      for (int m = 0; m < 4; m++) {
        #pragma unroll
        for (int reg = 0; reg < 4; reg++) {
          int grow = m0 + wr * 64 + m * 16 + q4 * 4 + reg;
          int b = grow >> 11, t = grow & 2047;
          u16 val = f2bf(acc[m][n][reg] + bv);
          if (which == 0)
            q_out[(((size_t)(b * NHEAD + h) * TT + t) << 6) + d] = val;
          else if (which == 1)
            k_out[(((size_t)(b * NHEAD + h) * TT + t) << 6) + d] = val;
          else  // V transposed: [b][h][d][t]
            v_out[(((size_t)(b * NHEAD + h) * HD + d) * TT) + t] = val;
        }
      }
    }
  } else {
    #pragma unroll
    for (int m = 0; m < 4; m++) {
      #pragma unroll
      for (int reg = 0; reg < 4; reg++) {
        int grow = m0 + wr * 64 + m * 16 + q4 * 4 + reg;
        #pragma unroll
        for (int n = 0; n < 4; n++) {
          int gcol = n0 + wc * 64 + n * 16 + r;
          c_out[(size_t)grow * N + gcol] = acc[m][n][reg] + bias[gcol];
        }
      }
    }
  }
}

// ---------------- causal flash attention, split-K quarters + backfill ----------------
// 2048 blocks of 256 (4 waves); one q-tile (32 rows) per block, k-range split
// into QUARTERS across the block's 4 waves -> all waves retire together.
// 8 blocks/CU of work vs 4 resident -> hardware backfills short blocks
// (dynamic cross-CU balance; R9/R10's fully-resident grids couldn't).
// Longest-first dispatch (wt = 63-tt). 4-way LDS merge: waves 1-3 post
// (m,l,O), wave 0 combines + writes Y. NO launch_bounds min-waves (R7/R8 bug).
#define SCL2 0.18033688011112042f   // 0.125 * log2(e)
#define MF 36                        // merge fields per lane: 32 O + m0,l0,m1,l1

__device__ __forceinline__ void attn_tile(
    const u16* __restrict__ Kp, const u16* __restrict__ Vp,
    const bf16x8 (&kin)[8], bf16x8 (&kout)[8],
    const bf16x8 (&qf)[2][2], f32x4 (&of)[2][4],
    float (&m_run)[2], float (&lp)[2],
    u16* pw, int kt, bool diag, int q0, int r, int q4)
{
  // 1) prefetch next K tile into kout (overfetch past range end is harmless)
  {
    const u16* kp = Kp + (size_t)(kt + 1) * (64 * HD);
    #pragma unroll
    for (int n = 0; n < 4; n++) {
      kout[n * 2 + 0] = *reinterpret_cast<const bf16x8*>(kp + n * 1024);
      kout[n * 2 + 1] = *reinterpret_cast<const bf16x8*>(kp + n * 1024 + 32);
    }
  }

  // 2) S^T = mfma(K, Q): sf[g][n][reg] = S[k][q], lane's q = q0+g*16+r
  f32x4 sf[2][4];
  __builtin_amdgcn_s_setprio(1);
  #pragma unroll
  for (int g = 0; g < 2; g++)
    #pragma unroll
    for (int n = 0; n < 4; n++) {
      f32x4 a = {0.f, 0.f, 0.f, 0.f};
      a = __builtin_amdgcn_mfma_f32_16x16x32_bf16(kin[n * 2 + 0], qf[g][0], a, 0, 0, 0);
      a = __builtin_amdgcn_mfma_f32_16x16x32_bf16(kin[n * 2 + 1], qf[g][1], a, 0, 0, 0);
      sf[g][n] = a;
    }
  __builtin_amdgcn_s_setprio(0);

  // 3) V fragments for this tile (latency hides under softmax)
  bf16x8 vf[2][4];
  #pragma unroll
  for (int d0 = 0; d0 < 4; d0++) {
    const u16* vp = Vp + (size_t)d0 * (16 * TT) + kt * 64;
    vf[0][d0] = *reinterpret_cast<const bf16x8*>(vp);
    vf[1][d0] = *reinterpret_cast<const bf16x8*>(vp + 32);
  }

  // 4) per-group in-lane online softmax
  #pragma unroll
  for (int g = 0; g < 2; g++) {
    const int myq = q0 + g * 16 + r;
    #pragma unroll
    for (int n = 0; n < 4; n++)
      #pragma unroll
      for (int reg = 0; reg < 4; reg++) {
        float s = sf[g][n][reg] * SCL2;
        if (diag) {
          int kg = kt * 64 + n * 16 + q4 * 4 + reg;
          if (kg > myq) s = -1e30f;
        }
        sf[g][n][reg] = s;
      }
    float a0 = fmaxf(fmaxf(sf[g][0][0], sf[g][0][1]), fmaxf(sf[g][0][2], sf[g][0][3]));
    float a1 = fmaxf(fmaxf(sf[g][1][0], sf[g][1][1]), fmaxf(sf[g][1][2], sf[g][1][3]));
    float a2 = fmaxf(fmaxf(sf[g][2][0], sf[g][2][1]), fmaxf(sf[g][2][2], sf[g][2][3]));
    float a3 = fmaxf(fmaxf(sf[g][3][0], sf[g][3][1]), fmaxf(sf[g][3][2], sf[g][3][3]));
    float mt = fmaxf(fmaxf(a0, a1), fmaxf(a2, a3));
    mt = fmaxf(mt, __shfl_xor(mt, 16));
    mt = fmaxf(mt, __shfl_xor(mt, 32));
    float mnew = fmaxf(m_run[g], mt);
    float alpha = __builtin_amdgcn_exp2f(m_run[g] - mnew);
    m_run[g] = mnew;

    f32x4 ss = {0.f, 0.f, 0.f, 0.f};
    #pragma unroll
    for (int n = 0; n < 4; n++) {
      #pragma unroll
      for (int reg = 0; reg < 4; reg++)
        sf[g][n][reg] = __builtin_amdgcn_exp2f(sf[g][n][reg] - mnew);
      ss += sf[g][n];
    }
    lp[g] = lp[g] * alpha + ((ss[0] + ss[1]) + (ss[2] + ss[3]));

    #pragma unroll
    for (int d0 = 0; d0 < 4; d0++)
      #pragma unroll
      for (int reg = 0; reg < 4; reg++)
        of[g][d0][reg] *= alpha;

    // P -> per-wave LDS [q][k] (packed 8B writes; no barrier needed)
    #pragma unroll
    for (int n = 0; n < 4; n++) {
      uint2 pk;
      pk.x = pack2bf(sf[g][n][0], sf[g][n][1]);
      pk.y = pack2bf(sf[g][n][2], sf[g][n][3]);
      *reinterpret_cast<uint2*>(&pw[(g * 16 + r) * 72 + n * 16 + q4 * 4]) = pk;
    }
  }

  // 5) O^T += mfma(V, P)
  #pragma unroll
  for (int g = 0; g < 2; g++)
    #pragma unroll
    for (int kc = 0; kc < 2; kc++) {
      bf16x8 pa = *reinterpret_cast<const bf16x8*>(&pw[(g * 16 + r) * 72 + kc * 32 + q4 * 8]);
      #pragma unroll
      for (int d0 = 0; d0 < 4; d0++)
        of[g][d0] = __builtin_amdgcn_mfma_f32_16x16x32_bf16(vf[kc][d0], pa, of[g][d0], 0, 0, 0);
    }
}

__global__ __launch_bounds__(256)
void k_attn(const u16* __restrict__ Q, const u16* __restrict__ Kk,
            const u16* __restrict__ Vt, u16* __restrict__ Y)
{
  // shared: during loop, 4 per-wave P tiles (4*4608B = 18432B at front);
  // after barrier, 3 merge slots of MF*64 floats each (field-major, conflict-free)
  __shared__ __align__(16) float msh[3 * MF * 64];   // 27648 B

  const int u = threadIdx.x;
  const int lane = u & 63;
  const int w = u >> 6;                 // 0..3
  const int r = lane & 15, q4 = lane >> 4;
  // XCD-resident head map: all 64 blocks of a head share blockIdx&7
  const int xcd = blockIdx.x & 7;
  const int j = blockIdx.x >> 3;        // 0..255
  const int bh = xcd * 4 + (j >> 6);    // 0..31 (4 heads per XCD)
  const int tt = j & 63;                // 0..63
  const int wt = 63 - tt;               // longest-first dispatch
  const int b = bh >> 4, h = bh & 15;
  const size_t head_off = (size_t)bh * TT * HD;   // Q,K: [t][d];  Vt: [d][t]
  const int q0 = wt * 32;
  const int c = (wt >> 1) + 1;          // total 64-col k-tiles for this q-tile
  const int kt0 = (c * w) >> 2;         // this wave's quarter
  const int kte = (c * (w + 1)) >> 2;

  const u16* Kp = Kk + head_off + (size_t)r * HD + q4 * 8;
  const u16* Vp = Vt + head_off + (size_t)r * TT + q4 * 8;

  bf16x8 qf[2][2];
  #pragma unroll
  for (int g = 0; g < 2; g++) {
    const u16* qp = &Q[head_off + (size_t)(q0 + g * 16 + r) * HD + q4 * 8];
    qf[g][0] = *reinterpret_cast<const bf16x8*>(qp);
    qf[g][1] = *reinterpret_cast<const bf16x8*>(qp + 32);
  }

  f32x4 of[2][4];
  #pragma unroll
  for (int g = 0; g < 2; g++)
    #pragma unroll
    for (int k = 0; k < 4; k++) of[g][k] = {0.f, 0.f, 0.f, 0.f};
  float m_run[2] = {-1e30f, -1e30f};
  float lp[2] = {0.f, 0.f};

  u16* pw = reinterpret_cast<u16*>(msh) + w * (32 * 72);

  // prologue: load K tile kt0 into kfA (garbage read for empty quarter is harmless)
  bf16x8 kfA[8], kfB[8];
  {
    const u16* kp = Kp + (size_t)kt0 * (64 * HD);
    #pragma unroll
    for (int n = 0; n < 4; n++) {
      kfA[n * 2 + 0] = *reinterpret_cast<const bf16x8*>(kp + n * 1024);
      kfA[n * 2 + 1] = *reinterpret_cast<const bf16x8*>(kp + n * 1024 + 32);
    }
  }

  for (int kt = kt0; kt < kte; kt += 2) {
    attn_tile(Kp, Vp, kfA, kfB, qf, of, m_run, lp, pw, kt, kt == c - 1, q0, r, q4);
    if (kt + 1 < kte)
      attn_tile(Kp, Vp, kfB, kfA, qf, of, m_run, lp, pw, kt + 1, kt + 1 == c - 1, q0, r, q4);
  }

  // ---- 4-way split-K merge (field-major [MF][64] slots, conflict-free) ----
  __syncthreads();                      // all P-tile reads done; msh reusable
  if (w != 0) {
    float* mb = msh + (w - 1) * (MF * 64) + lane;
    #pragma unroll
    for (int g = 0; g < 2; g++) {
      #pragma unroll
      for (int d0 = 0; d0 < 4; d0++)
        #pragma unroll
        for (int jj = 0; jj < 4; jj++)
          mb[(g * 16 + d0 * 4 + jj) * 64] = of[g][d0][jj];
      mb[(32 + g * 2 + 0) * 64] = m_run[g];
      mb[(32 + g * 2 + 1) * 64] = lp[g];
    }
  }
  __syncthreads();
  if (w == 0) {
    #pragma unroll
    for (int g = 0; g < 2; g++) {
      float ms[3], ls[3];
      #pragma unroll
      for (int s = 0; s < 3; s++) {
        ms[s] = msh[s * (MF * 64) + (32 + g * 2 + 0) * 64 + lane];
        ls[s] = msh[s * (MF * 64) + (32 + g * 2 + 1) * 64 + lane];
      }
      float M = fmaxf(fmaxf(m_run[g], ms[0]), fmaxf(ms[1], ms[2]));
      float aown = __builtin_amdgcn_exp2f(m_run[g] - M);
      float l = lp[g] * aown;
      #pragma unroll
      for (int d0 = 0; d0 < 4; d0++)
        #pragma unroll
        for (int jj = 0; jj < 4; jj++)
          of[g][d0][jj] *= aown;
      #pragma unroll
      for (int s = 0; s < 3; s++) {
        float a = __builtin_amdgcn_exp2f(ms[s] - M);
        l += ls[s] * a;
        const float* mb = msh + s * (MF * 64) + lane;
        #pragma unroll
        for (int d0 = 0; d0 < 4; d0++)
          #pragma unroll
          for (int jj = 0; jj < 4; jj++)
            of[g][d0][jj] += mb[(g * 16 + d0 * 4 + jj) * 64] * a;
      }
      l += __shfl_xor(l, 16);
      l += __shfl_xor(l, 32);
      float inv = 1.0f / l;
      const int t2 = q0 + g * 16 + r;
      #pragma unroll
      for (int d0 = 0; d0 < 4; d0++) {
        uint2 pk;
        pk.x = pack2bf(of[g][d0][0] * inv, of[g][d0][1] * inv);
        pk.y = pack2bf(of[g][d0][2] * inv, of[g][d0][3] * inv);
        *reinterpret_cast<uint2*>(&Y[((size_t)(b * TT + t2) << 10) + h * 64 + d0 * 16 + q4 * 4]) = pk;
      }
    }
  }
}

// ---------------- host launcher ----------------
extern "C" void kernel_launch(void* const* d_in, const int* in_sizes, int n_in,
                              void* d_out, int out_size, void* d_ws, size_t ws_size,
                              hipStream_t stream) {
  const float* x     = (const float*)d_in[0];
  const float* w_qkv = (const float*)d_in[1];
  const float* b_qkv = (const float*)d_in[2];
  const float* w_out = (const float*)d_in[3];
  const float* b_out = (const float*)d_in[4];
  float* out = (float*)d_out;

  uint8_t* ws = (uint8_t*)d_ws;
  u16* xb    = (u16*)(ws);                    // 8 MB  (reused as y_heads later)
  u16* wqkvT = (u16*)(ws + (8u  << 20));      // 6 MB
  u16* woutT = (u16*)(ws + (14u << 20));      // 2 MB
  u16* Qh    = (u16*)(ws + (16u << 20));      // 8 MB
  u16* Kh    = (u16*)(ws + (24u << 20));      // 8 MB
  u16* Vth   = (u16*)(ws + (32u << 20));      // 8 MB  (transposed V; also absorbs K prefetch overfetch)

  k_f32_to_bf16<<<1024, 256, 0, stream>>>(x, xb, (MR * D_MODEL) / 4);
  k_transpose_both<<<dim3(128, D_MODEL / 32), dim3(32, 8), 0, stream>>>(
      w_qkv, w_out, wqkvT, woutT);

  k_gemm_bt<0><<<dim3(3 * D_MODEL / 128, MR / 128), 256, 0, stream>>>(
      xb, wqkvT, b_qkv, Qh, Kh, Vth, nullptr, MR, 3 * D_MODEL, D_MODEL);

  u16* Yh = xb;  // reuse x-bf16 region
  k_attn<<<dim3(2048), dim3(256), 0, stream>>>(Qh, Kh, Vth, Yh);

  k_gemm_bt<1><<<dim3(D_MODEL / 128, MR / 128), 256, 0, stream>>>(
      Yh, woutT, b_out, nullptr, nullptr, nullptr, out, MR, D_MODEL, D_MODEL);
}

// Round 12
// 169.581 us; speedup vs baseline: 1.1852x; 1.0968x over previous
//
#include <hip/hip_runtime.h>
#include <stdint.h>

#define D_MODEL 1024
#define NHEAD 16
#define HD 64
#define BB 2
#define TT 2048
#define MR (BB*TT)   // 4096 rows

#define SCL2 0.18033688011112042f   // 0.125 * log2(e), folded into Q at projection

typedef unsigned short u16;
typedef __bf16 bf16x8 __attribute__((ext_vector_type(8)));
typedef __bf16 bf16x4v __attribute__((ext_vector_type(4)));
typedef u16 u16x8 __attribute__((ext_vector_type(8)));
typedef float f32x4 __attribute__((ext_vector_type(4)));

__device__ __forceinline__ u16 f2bf(float f) {
  union { float f; unsigned u; } v; v.f = f;
  unsigned r = v.u + 0x7FFFu + ((v.u >> 16) & 1u);
  return (u16)(r >> 16);
}

__device__ __forceinline__ void gload_lds16(const void* g, void* l) {
  __builtin_amdgcn_global_load_lds(
      (const __attribute__((address_space(1))) void*)g,
      (__attribute__((address_space(3))) void*)l, 16, 0, 0);
}

// ---------------- f32 -> bf16 convert (vectorized) ----------------
__global__ void k_f32_to_bf16(const float* __restrict__ src, u16* __restrict__ dst, int n4) {
  int idx = blockIdx.x * blockDim.x + threadIdx.x;
  int stride = gridDim.x * blockDim.x;
  for (int i = idx; i < n4; i += stride) {
    float4 v = reinterpret_cast<const float4*>(src)[i];
    ushort4 o;
    o.x = f2bf(v.x); o.y = f2bf(v.y); o.z = f2bf(v.z); o.w = f2bf(v.w);
    reinterpret_cast<ushort4*>(dst)[i] = o;
  }
}

// ---------------- transpose f32 [K][N] -> bf16 [N][K], both weights fused ----------------
__global__ void k_transpose_both(const float* __restrict__ wqkv, const float* __restrict__ wout,
                                 u16* __restrict__ dqkv, u16* __restrict__ dout) {
  __shared__ float tile[32][33];
  int bx = blockIdx.x;
  const float* src; u16* dst; int N; int n0;
  if (bx < 96) { src = wqkv; dst = dqkv; N = 3 * D_MODEL; n0 = bx * 32; }
  else         { src = wout; dst = dout; N = D_MODEL;     n0 = (bx - 96) * 32; }
  const int K = D_MODEL;
  int k0 = blockIdx.y * 32;
  int tx = threadIdx.x, ty = threadIdx.y;  // block (32,8)
  #pragma unroll
  for (int i = 0; i < 32; i += 8)
    tile[ty + i][tx] = src[(size_t)(k0 + ty + i) * N + n0 + tx];
  __syncthreads();
  #pragma unroll
  for (int i = 0; i < 32; i += 8)
    dst[(size_t)(n0 + ty + i) * K + k0 + tx] = f2bf(tile[tx][ty + i]);
}

// ---------------- bf16 GEMM, B^T input, 128x128 tile ----------------
// MODE 0: qkv projection -> Q (pre-scaled by SCL2) / K into [B][H][T][64],
//         V into [B][H][64][T] (transposed), +bias
// MODE 1: out = A @ B + bias, f32 row-major
template<int MODE>
__global__ __launch_bounds__(256)
void k_gemm_bt(const u16* __restrict__ A, const u16* __restrict__ Bt,
               const float* __restrict__ bias,
               u16* __restrict__ q_out, u16* __restrict__ k_out, u16* __restrict__ v_out,
               float* __restrict__ c_out, int M, int N, int K)
{
  __shared__ __align__(16) u16 a_sh[128 * 64];
  __shared__ __align__(16) u16 b_sh[128 * 64];
  const int u = threadIdx.x;
  const int lane = u & 63;
  const int w = u >> 6;
  const int wr = w >> 1, wc = w & 1;
  const int m0 = blockIdx.y * 128;
  const int n0 = blockIdx.x * 128;
  const int r = lane & 15, q4 = lane >> 4;

  f32x4 acc[4][4];
  #pragma unroll
  for (int i = 0; i < 4; i++)
    #pragma unroll
    for (int j = 0; j < 4; j++) acc[i][j] = {0.f, 0.f, 0.f, 0.f};

  const int arow = u >> 3;        // 0..31
  const int acol = (u & 7) * 8;   // 0..56
  const u16* Ag = A + (size_t)(m0 + arow) * K + acol;
  const u16* Bg = Bt + (size_t)(n0 + arow) * K + acol;

  for (int k0 = 0; k0 < K; k0 += 64) {
    #pragma unroll
    for (int i = 0; i < 4; i++) {
      gload_lds16(Ag + (size_t)i * 32 * K + k0, &a_sh[(i * 32 + w * 8) * 64]);
      gload_lds16(Bg + (size_t)i * 32 * K + k0, &b_sh[(i * 32 + w * 8) * 64]);
    }
    __syncthreads();
    #pragma unroll
    for (int kc = 0; kc < 2; kc++) {
      bf16x8 af[4], bfr[4];
      #pragma unroll
      for (int m = 0; m < 4; m++)
        af[m] = *reinterpret_cast<const bf16x8*>(&a_sh[(wr * 64 + m * 16 + r) * 64 + kc * 32 + q4 * 8]);
      #pragma unroll
      for (int n = 0; n < 4; n++)
        bfr[n] = *reinterpret_cast<const bf16x8*>(&b_sh[(wc * 64 + n * 16 + r) * 64 + kc * 32 + q4 * 8]);
      #pragma unroll
      for (int m = 0; m < 4; m++)
        #pragma unroll
        for (int n = 0; n < 4; n++)
          acc[m][n] = __builtin_amdgcn_mfma_f32_16x16x32_bf16(af[m], bfr[n], acc[m][n], 0, 0, 0);
    }
    __syncthreads();
  }

  if (MODE == 0) {
    #pragma unroll
    for (int n = 0; n < 4; n++) {
      int gcol = n0 + wc * 64 + n * 16 + r;
      int which = gcol >> 10;   // uniform within fragment (16-aligned ranges)
      int rem = gcol & 1023;
      int h = rem >> 6, d = rem & 63;
      float bv = bias[gcol];
      #pragma unroll
      for (int m = 0; m < 4; m++) {
        #pragma unroll
        for (int reg = 0; reg < 4; reg++) {
          int grow = m0 + wr * 64 + m * 16 + q4 * 4 + reg;
          int b = grow >> 11, t = grow & 2047;
          float fv = acc[m][n][reg] + bv;
          if (which == 0)
            q_out[(((size_t)(b * NHEAD + h) * TT + t) << 6) + d] = f2bf(fv * SCL2);
          else if (which == 1)
            k_out[(((size_t)(b * NHEAD + h) * TT + t) << 6) + d] = f2bf(fv);
          else  // V transposed: [b][h][d][t]
            v_out[(((size_t)(b * NHEAD + h) * HD + d) * TT) + t] = f2bf(fv);
        }
      }
    }
  } else {
    #pragma unroll
    for (int m = 0; m < 4; m++) {
      #pragma unroll
      for (int reg = 0; reg < 4; reg++) {
        int grow = m0 + wr * 64 + m * 16 + q4 * 4 + reg;
        #pragma unroll
        for (int n = 0; n < 4; n++) {
          int gcol = n0 + wc * 64 + n * 16 + r;
          c_out[(size_t)grow * N + gcol] = acc[m][n][reg] + bias[gcol];
        }
      }
    }
  }
}

// ---------------- causal flash attention ----------------
// R6 structure (best measured): 256 blocks of 512 (8 independent waves), each
// wave owns 32 q-rows; SIMD s hosts waves s (tile 4i+s) and s+4 (tile 63-4i-s)
// -> per-SIMD totals constant. Swapped operands keep softmax in-lane; K tiles
// register double-buffered; barrier-free.
// VALU diet vs R6: Q pre-scaled (no per-iter scale), defer-max THR=6 (common
// case skips shfl-max + rescale + alpha exp2), native bf16 casts (cvt_pk).
#define DEFER_THR 6.0f

__device__ __forceinline__ void attn_tile(
    const u16* __restrict__ Kp, const u16* __restrict__ Vp,
    const bf16x8 (&kin)[8], bf16x8 (&kout)[8],
    const bf16x8 (&qf)[2][2], f32x4 (&of)[2][4],
    float (&m_run)[2], float (&lp)[2],
    u16* pw, int kt, bool diag, int q0, int r, int q4)
{
  // 1) prefetch next K tile into kout (overfetch past range end is harmless)
  {
    const u16* kp = Kp + (size_t)(kt + 1) * (64 * HD);
    #pragma unroll
    for (int n = 0; n < 4; n++) {
      kout[n * 2 + 0] = *reinterpret_cast<const bf16x8*>(kp + n * 1024);
      kout[n * 2 + 1] = *reinterpret_cast<const bf16x8*>(kp + n * 1024 + 32);
    }
  }

  // 2) S^T = mfma(K, Q): sf[g][n][reg] = S[k][q] (log2-domain: Q pre-scaled)
  f32x4 sf[2][4];
  __builtin_amdgcn_s_setprio(1);
  #pragma unroll
  for (int g = 0; g < 2; g++)
    #pragma unroll
    for (int n = 0; n < 4; n++) {
      f32x4 a = {0.f, 0.f, 0.f, 0.f};
      a = __builtin_amdgcn_mfma_f32_16x16x32_bf16(kin[n * 2 + 0], qf[g][0], a, 0, 0, 0);
      a = __builtin_amdgcn_mfma_f32_16x16x32_bf16(kin[n * 2 + 1], qf[g][1], a, 0, 0, 0);
      sf[g][n] = a;
    }
  __builtin_amdgcn_s_setprio(0);

  // 3) V fragments for this tile (latency hides under softmax)
  bf16x8 vf[2][4];
  #pragma unroll
  for (int d0 = 0; d0 < 4; d0++) {
    const u16* vp = Vp + (size_t)d0 * (16 * TT) + kt * 64;
    vf[0][d0] = *reinterpret_cast<const bf16x8*>(vp);
    vf[1][d0] = *reinterpret_cast<const bf16x8*>(vp + 32);
  }

  // 4) per-group in-lane online softmax with deferred max
  #pragma unroll
  for (int g = 0; g < 2; g++) {
    const int myq = q0 + g * 16 + r;
    if (diag) {
      #pragma unroll
      for (int n = 0; n < 4; n++)
        #pragma unroll
        for (int reg = 0; reg < 4; reg++) {
          int kg = kt * 64 + n * 16 + q4 * 4 + reg;
          if (kg > myq) sf[g][n][reg] = -1e30f;
        }
    }
    // local max over this lane's 16 values (v_max3-friendly triples)
    float ma = fmaxf(fmaxf(sf[g][0][0], sf[g][0][1]), sf[g][0][2]);
    float mb = fmaxf(fmaxf(sf[g][0][3], sf[g][1][0]), sf[g][1][1]);
    float mc = fmaxf(fmaxf(sf[g][1][2], sf[g][1][3]), sf[g][2][0]);
    float md = fmaxf(fmaxf(sf[g][2][1], sf[g][2][2]), sf[g][2][3]);
    float me = fmaxf(fmaxf(sf[g][3][0], sf[g][3][1]), sf[g][3][2]);
    float mt = fmaxf(fmaxf(fmaxf(ma, mb), fmaxf(mc, md)), fmaxf(me, sf[g][3][3]));

    if (!__all(mt <= m_run[g] + DEFER_THR)) {
      float fm = fmaxf(mt, __shfl_xor(mt, 16));
      fm = fmaxf(fm, __shfl_xor(fm, 32));
      float mnew = fmaxf(m_run[g], fm);
      float alpha = __builtin_amdgcn_exp2f(m_run[g] - mnew);
      lp[g] *= alpha;
      #pragma unroll
      for (int d0 = 0; d0 < 4; d0++)
        of[g][d0] *= alpha;
      m_run[g] = mnew;
    }

    f32x4 ss = {0.f, 0.f, 0.f, 0.f};
    #pragma unroll
    for (int n = 0; n < 4; n++) {
      #pragma unroll
      for (int reg = 0; reg < 4; reg++)
        sf[g][n][reg] = __builtin_amdgcn_exp2f(sf[g][n][reg] - m_run[g]);
      ss += sf[g][n];
    }
    lp[g] += (ss[0] + ss[1]) + (ss[2] + ss[3]);

    // P -> per-wave LDS [q][k] via native bf16 casts (v_cvt_pk) + 8B writes
    #pragma unroll
    for (int n = 0; n < 4; n++) {
      bf16x4v pv;
      pv[0] = (__bf16)sf[g][n][0]; pv[1] = (__bf16)sf[g][n][1];
      pv[2] = (__bf16)sf[g][n][2]; pv[3] = (__bf16)sf[g][n][3];
      *reinterpret_cast<bf16x4v*>(&pw[(g * 16 + r) * 72 + n * 16 + q4 * 4]) = pv;
    }
  }

  // 5) O^T += mfma(V, P)
  #pragma unroll
  for (int g = 0; g < 2; g++)
    #pragma unroll
    for (int kc = 0; kc < 2; kc++) {
      bf16x8 pa = *reinterpret_cast<const bf16x8*>(&pw[(g * 16 + r) * 72 + kc * 32 + q4 * 8]);
      #pragma unroll
      for (int d0 = 0; d0 < 4; d0++)
        of[g][d0] = __builtin_amdgcn_mfma_f32_16x16x32_bf16(vf[kc][d0], pa, of[g][d0], 0, 0, 0);
    }
}

__global__ __launch_bounds__(512)
void k_attn(const u16* __restrict__ Q, const u16* __restrict__ Kk,
            const u16* __restrict__ Vt, u16* __restrict__ Y)
{
  __shared__ __align__(16) u16 p_sh[8][32 * 72];   // per-wave [32 q][64 k] P tile

  const int u = threadIdx.x;
  const int lane = u & 63;
  const int w = u >> 6;                 // 0..7
  const int r = lane & 15, q4 = lane >> 4;
  // XCD-resident head map: all 8 blocks of a head share blockIdx&7
  const int xcd = blockIdx.x & 7;
  const int j = blockIdx.x >> 3;        // 0..31
  const int bh = xcd * 4 + (j >> 3);    // 0..31
  const int i = j & 7;                  // block index within head, 0..7
  const int s = w & 3, half = w >> 2;
  const int wt = half ? (63 - (4 * i + s)) : (4 * i + s);   // SIMD s: cheap+expensive pair
  const int b = bh >> 4, h = bh & 15;
  const size_t head_off = (size_t)bh * TT * HD;   // Q,K: [t][d];  Vt: [d][t]
  const int q0 = wt * 32;
  const int lastkt = wt >> 1;

  const u16* Kp = Kk + head_off + (size_t)r * HD + q4 * 8;
  const u16* Vp = Vt + head_off + (size_t)r * TT + q4 * 8;

  bf16x8 qf[2][2];
  #pragma unroll
  for (int g = 0; g < 2; g++) {
    const u16* qp = &Q[head_off + (size_t)(q0 + g * 16 + r) * HD + q4 * 8];
    qf[g][0] = *reinterpret_cast<const bf16x8*>(qp);
    qf[g][1] = *reinterpret_cast<const bf16x8*>(qp + 32);
  }

  f32x4 of[2][4];
  #pragma unroll
  for (int g = 0; g < 2; g++)
    #pragma unroll
    for (int k = 0; k < 4; k++) of[g][k] = {0.f, 0.f, 0.f, 0.f};
  float m_run[2] = {-1e30f, -1e30f};
  float lp[2] = {0.f, 0.f};

  u16* pw = &p_sh[w][0];

  // prologue: load K tile 0 into kfA
  bf16x8 kfA[8], kfB[8];
  #pragma unroll
  for (int n = 0; n < 4; n++) {
    kfA[n * 2 + 0] = *reinterpret_cast<const bf16x8*>(Kp + n * 1024);
    kfA[n * 2 + 1] = *reinterpret_cast<const bf16x8*>(Kp + n * 1024 + 32);
  }

  for (int kt = 0; kt <= lastkt; kt += 2) {
    attn_tile(Kp, Vp, kfA, kfB, qf, of, m_run, lp, pw, kt, kt == lastkt, q0, r, q4);
    if (kt + 1 <= lastkt)
      attn_tile(Kp, Vp, kfB, kfA, qf, of, m_run, lp, pw, kt + 1, kt + 1 == lastkt, q0, r, q4);
  }

  // epilogue: reduce per-lane partial l across q4 lanes, packed bf16 stores
  #pragma unroll
  for (int g = 0; g < 2; g++) {
    float l = lp[g];
    l += __shfl_xor(l, 16);
    l += __shfl_xor(l, 32);
    float inv = 1.0f / l;
    const int t = q0 + g * 16 + r;
    #pragma unroll
    for (int d0 = 0; d0 < 4; d0++) {
      bf16x4v yv;
      yv[0] = (__bf16)(of[g][d0][0] * inv); yv[1] = (__bf16)(of[g][d0][1] * inv);
      yv[2] = (__bf16)(of[g][d0][2] * inv); yv[3] = (__bf16)(of[g][d0][3] * inv);
      *reinterpret_cast<bf16x4v*>(&Y[((size_t)(b * TT + t) << 10) + h * 64 + d0 * 16 + q4 * 4]) = yv;
    }
  }
}

// ---------------- host launcher ----------------
extern "C" void kernel_launch(void* const* d_in, const int* in_sizes, int n_in,
                              void* d_out, int out_size, void* d_ws, size_t ws_size,
                              hipStream_t stream) {
  const float* x     = (const float*)d_in[0];
  const float* w_qkv = (const float*)d_in[1];
  const float* b_qkv = (const float*)d_in[2];
  const float* w_out = (const float*)d_in[3];
  const float* b_out = (const float*)d_in[4];
  float* out = (float*)d_out;

  uint8_t* ws = (uint8_t*)d_ws;
  u16* xb    = (u16*)(ws);                    // 8 MB  (reused as y_heads later)
  u16* wqkvT = (u16*)(ws + (8u  << 20));      // 6 MB
  u16* woutT = (u16*)(ws + (14u << 20));      // 2 MB
  u16* Qh    = (u16*)(ws + (16u << 20));      // 8 MB
  u16* Kh    = (u16*)(ws + (24u << 20));      // 8 MB
  u16* Vth   = (u16*)(ws + (32u << 20));      // 8 MB  (transposed V; also absorbs K prefetch overfetch)

  k_f32_to_bf16<<<1024, 256, 0, stream>>>(x, xb, (MR * D_MODEL) / 4);
  k_transpose_both<<<dim3(128, D_MODEL / 32), dim3(32, 8), 0, stream>>>(
      w_qkv, w_out, wqkvT, woutT);

  k_gemm_bt<0><<<dim3(3 * D_MODEL / 128, MR / 128), 256, 0, stream>>>(
      xb, wqkvT, b_qkv, Qh, Kh, Vth, nullptr, MR, 3 * D_MODEL, D_MODEL);

  u16* Yh = xb;  // reuse x-bf16 region
  k_attn<<<dim3(256), dim3(512), 0, stream>>>(Qh, Kh, Vth, Yh);

  k_gemm_bt<1><<<dim3(D_MODEL / 128, MR / 128), 256, 0, stream>>>(
      Yh, woutT, b_out, nullptr, nullptr, nullptr, out, MR, D_MODEL, D_MODEL);
}

// Round 13
// 154.874 us; speedup vs baseline: 1.2977x; 1.0950x over previous
//
#include <hip/hip_runtime.h>
#include <stdint.h>

#define D_MODEL 1024
#define NHEAD 16
#define HD 64
#define BB 2
#define TT 2048
#define MR (BB*TT)   // 4096 rows

#define SCL2 0.18033688011112042f   // 0.125 * log2(e), folded into Q at projection

typedef unsigned short u16;
typedef __bf16 bf16x8 __attribute__((ext_vector_type(8)));
typedef __bf16 bf16x4v __attribute__((ext_vector_type(4)));
typedef u16 u16x8 __attribute__((ext_vector_type(8)));
typedef float f32x4 __attribute__((ext_vector_type(4)));

__device__ __forceinline__ u16 f2bf(float f) {
  union { float f; unsigned u; } v; v.f = f;
  unsigned r = v.u + 0x7FFFu + ((v.u >> 16) & 1u);
  return (u16)(r >> 16);
}

__device__ __forceinline__ void gload_lds16(const void* g, void* l) {
  __builtin_amdgcn_global_load_lds(
      (const __attribute__((address_space(1))) void*)g,
      (__attribute__((address_space(3))) void*)l, 16, 0, 0);
}

// ---------------- f32 -> bf16 convert (vectorized) ----------------
__global__ void k_f32_to_bf16(const float* __restrict__ src, u16* __restrict__ dst, int n4) {
  int idx = blockIdx.x * blockDim.x + threadIdx.x;
  int stride = gridDim.x * blockDim.x;
  for (int i = idx; i < n4; i += stride) {
    float4 v = reinterpret_cast<const float4*>(src)[i];
    ushort4 o;
    o.x = f2bf(v.x); o.y = f2bf(v.y); o.z = f2bf(v.z); o.w = f2bf(v.w);
    reinterpret_cast<ushort4*>(dst)[i] = o;
  }
}

// ---------------- transpose f32 [K][N] -> bf16 [N][K], both weights fused ----------------
__global__ void k_transpose_both(const float* __restrict__ wqkv, const float* __restrict__ wout,
                                 u16* __restrict__ dqkv, u16* __restrict__ dout) {
  __shared__ float tile[32][33];
  int bx = blockIdx.x;
  const float* src; u16* dst; int N; int n0;
  if (bx < 96) { src = wqkv; dst = dqkv; N = 3 * D_MODEL; n0 = bx * 32; }
  else         { src = wout; dst = dout; N = D_MODEL;     n0 = (bx - 96) * 32; }
  const int K = D_MODEL;
  int k0 = blockIdx.y * 32;
  int tx = threadIdx.x, ty = threadIdx.y;  // block (32,8)
  #pragma unroll
  for (int i = 0; i < 32; i += 8)
    tile[ty + i][tx] = src[(size_t)(k0 + ty + i) * N + n0 + tx];
  __syncthreads();
  #pragma unroll
  for (int i = 0; i < 32; i += 8)
    dst[(size_t)(n0 + ty + i) * K + k0 + tx] = f2bf(tile[tx][ty + i]);
}

// ---------------- bf16 GEMM, B^T input, 128x64 tile (occupancy-optimized) ----------------
// 4 waves, each owns 32 rows x 64 cols (2x4 fragments). Grid: MODE0 48x32=1536
// blocks (6/CU), MODE1 16x32=512 (2/CU) -- latency-bound regime scales with
// blocks/CU (m102 curve), so smaller N-tile > bigger reuse here.
// MODE 0: qkv projection -> Q (pre-scaled by SCL2) / K into [B][H][T][64],
//         V into [B][H][64][T] (transposed), +bias
// MODE 1: out = A @ B + bias, f32 row-major
template<int MODE>
__global__ __launch_bounds__(256)
void k_gemm_bt(const u16* __restrict__ A, const u16* __restrict__ Bt,
               const float* __restrict__ bias,
               u16* __restrict__ q_out, u16* __restrict__ k_out, u16* __restrict__ v_out,
               float* __restrict__ c_out, int M, int N, int K)
{
  __shared__ __align__(16) u16 a_sh[128 * 64];
  __shared__ __align__(16) u16 b_sh[64 * 64];
  const int u = threadIdx.x;
  const int lane = u & 63;
  const int w = u >> 6;           // wave = row quadrant (32 rows)
  const int m0 = blockIdx.y * 128;
  const int n0 = blockIdx.x * 64;
  const int r = lane & 15, q4 = lane >> 4;

  f32x4 acc[2][4];
  #pragma unroll
  for (int i = 0; i < 2; i++)
    #pragma unroll
    for (int j = 0; j < 4; j++) acc[i][j] = {0.f, 0.f, 0.f, 0.f};

  const int arow = u >> 3;        // 0..31
  const int acol = (u & 7) * 8;   // 0..56
  const u16* Ag = A + (size_t)(m0 + arow) * K + acol;
  const u16* Bg = Bt + (size_t)(n0 + arow) * K + acol;

  for (int k0 = 0; k0 < K; k0 += 64) {
    #pragma unroll
    for (int i = 0; i < 4; i++)
      gload_lds16(Ag + (size_t)i * 32 * K + k0, &a_sh[(i * 32 + w * 8) * 64]);
    #pragma unroll
    for (int i = 0; i < 2; i++)
      gload_lds16(Bg + (size_t)i * 32 * K + k0, &b_sh[(i * 32 + w * 8) * 64]);
    __syncthreads();
    #pragma unroll
    for (int kc = 0; kc < 2; kc++) {
      bf16x8 af[2], bfr[4];
      #pragma unroll
      for (int m = 0; m < 2; m++)
        af[m] = *reinterpret_cast<const bf16x8*>(&a_sh[(w * 32 + m * 16 + r) * 64 + kc * 32 + q4 * 8]);
      #pragma unroll
      for (int n = 0; n < 4; n++)
        bfr[n] = *reinterpret_cast<const bf16x8*>(&b_sh[(n * 16 + r) * 64 + kc * 32 + q4 * 8]);
      #pragma unroll
      for (int m = 0; m < 2; m++)
        #pragma unroll
        for (int n = 0; n < 4; n++)
          acc[m][n] = __builtin_amdgcn_mfma_f32_16x16x32_bf16(af[m], bfr[n], acc[m][n], 0, 0, 0);
    }
    __syncthreads();
  }

  if (MODE == 0) {
    #pragma unroll
    for (int n = 0; n < 4; n++) {
      int gcol = n0 + n * 16 + r;
      int which = gcol >> 10;   // uniform within fragment (64-aligned n0)
      int rem = gcol & 1023;
      int h = rem >> 6, d = rem & 63;
      float bv = bias[gcol];
      #pragma unroll
      for (int m = 0; m < 2; m++) {
        #pragma unroll
        for (int reg = 0; reg < 4; reg++) {
          int grow = m0 + w * 32 + m * 16 + q4 * 4 + reg;
          int b = grow >> 11, t = grow & 2047;
          float fv = acc[m][n][reg] + bv;
          if (which == 0)
            q_out[(((size_t)(b * NHEAD + h) * TT + t) << 6) + d] = f2bf(fv * SCL2);
          else if (which == 1)
            k_out[(((size_t)(b * NHEAD + h) * TT + t) << 6) + d] = f2bf(fv);
          else  // V transposed: [b][h][d][t]
            v_out[(((size_t)(b * NHEAD + h) * HD + d) * TT) + t] = f2bf(fv);
        }
      }
    }
  } else {
    #pragma unroll
    for (int m = 0; m < 2; m++) {
      #pragma unroll
      for (int reg = 0; reg < 4; reg++) {
        int grow = m0 + w * 32 + m * 16 + q4 * 4 + reg;
        #pragma unroll
        for (int n = 0; n < 4; n++) {
          int gcol = n0 + n * 16 + r;
          c_out[(size_t)grow * N + gcol] = acc[m][n][reg] + bias[gcol];
        }
      }
    }
  }
}

// ---------------- causal flash attention (R12: VALU diet, unchanged) ----------------
#define DEFER_THR 6.0f

__device__ __forceinline__ void attn_tile(
    const u16* __restrict__ Kp, const u16* __restrict__ Vp,
    const bf16x8 (&kin)[8], bf16x8 (&kout)[8],
    const bf16x8 (&qf)[2][2], f32x4 (&of)[2][4],
    float (&m_run)[2], float (&lp)[2],
    u16* pw, int kt, bool diag, int q0, int r, int q4)
{
  // 1) prefetch next K tile into kout (overfetch past range end is harmless)
  {
    const u16* kp = Kp + (size_t)(kt + 1) * (64 * HD);
    #pragma unroll
    for (int n = 0; n < 4; n++) {
      kout[n * 2 + 0] = *reinterpret_cast<const bf16x8*>(kp + n * 1024);
      kout[n * 2 + 1] = *reinterpret_cast<const bf16x8*>(kp + n * 1024 + 32);
    }
  }

  // 2) S^T = mfma(K, Q): sf[g][n][reg] = S[k][q] (log2-domain: Q pre-scaled)
  f32x4 sf[2][4];
  __builtin_amdgcn_s_setprio(1);
  #pragma unroll
  for (int g = 0; g < 2; g++)
    #pragma unroll
    for (int n = 0; n < 4; n++) {
      f32x4 a = {0.f, 0.f, 0.f, 0.f};
      a = __builtin_amdgcn_mfma_f32_16x16x32_bf16(kin[n * 2 + 0], qf[g][0], a, 0, 0, 0);
      a = __builtin_amdgcn_mfma_f32_16x16x32_bf16(kin[n * 2 + 1], qf[g][1], a, 0, 0, 0);
      sf[g][n] = a;
    }
  __builtin_amdgcn_s_setprio(0);

  // 3) V fragments for this tile (latency hides under softmax)
  bf16x8 vf[2][4];
  #pragma unroll
  for (int d0 = 0; d0 < 4; d0++) {
    const u16* vp = Vp + (size_t)d0 * (16 * TT) + kt * 64;
    vf[0][d0] = *reinterpret_cast<const bf16x8*>(vp);
    vf[1][d0] = *reinterpret_cast<const bf16x8*>(vp + 32);
  }

  // 4) per-group in-lane online softmax with deferred max
  #pragma unroll
  for (int g = 0; g < 2; g++) {
    const int myq = q0 + g * 16 + r;
    if (diag) {
      #pragma unroll
      for (int n = 0; n < 4; n++)
        #pragma unroll
        for (int reg = 0; reg < 4; reg++) {
          int kg = kt * 64 + n * 16 + q4 * 4 + reg;
          if (kg > myq) sf[g][n][reg] = -1e30f;
        }
    }
    // local max over this lane's 16 values (v_max3-friendly triples)
    float ma = fmaxf(fmaxf(sf[g][0][0], sf[g][0][1]), sf[g][0][2]);
    float mb = fmaxf(fmaxf(sf[g][0][3], sf[g][1][0]), sf[g][1][1]);
    float mc = fmaxf(fmaxf(sf[g][1][2], sf[g][1][3]), sf[g][2][0]);
    float md = fmaxf(fmaxf(sf[g][2][1], sf[g][2][2]), sf[g][2][3]);
    float me = fmaxf(fmaxf(sf[g][3][0], sf[g][3][1]), sf[g][3][2]);
    float mt = fmaxf(fmaxf(fmaxf(ma, mb), fmaxf(mc, md)), fmaxf(me, sf[g][3][3]));

    if (!__all(mt <= m_run[g] + DEFER_THR)) {
      float fm = fmaxf(mt, __shfl_xor(mt, 16));
      fm = fmaxf(fm, __shfl_xor(fm, 32));
      float mnew = fmaxf(m_run[g], fm);
      float alpha = __builtin_amdgcn_exp2f(m_run[g] - mnew);
      lp[g] *= alpha;
      #pragma unroll
      for (int d0 = 0; d0 < 4; d0++)
        of[g][d0] *= alpha;
      m_run[g] = mnew;
    }

    f32x4 ss = {0.f, 0.f, 0.f, 0.f};
    #pragma unroll
    for (int n = 0; n < 4; n++) {
      #pragma unroll
      for (int reg = 0; reg < 4; reg++)
        sf[g][n][reg] = __builtin_amdgcn_exp2f(sf[g][n][reg] - m_run[g]);
      ss += sf[g][n];
    }
    lp[g] += (ss[0] + ss[1]) + (ss[2] + ss[3]);

    // P -> per-wave LDS [q][k] via native bf16 casts (v_cvt_pk) + 8B writes
    #pragma unroll
    for (int n = 0; n < 4; n++) {
      bf16x4v pv;
      pv[0] = (__bf16)sf[g][n][0]; pv[1] = (__bf16)sf[g][n][1];
      pv[2] = (__bf16)sf[g][n][2]; pv[3] = (__bf16)sf[g][n][3];
      *reinterpret_cast<bf16x4v*>(&pw[(g * 16 + r) * 72 + n * 16 + q4 * 4]) = pv;
    }
  }

  // 5) O^T += mfma(V, P)
  #pragma unroll
  for (int g = 0; g < 2; g++)
    #pragma unroll
    for (int kc = 0; kc < 2; kc++) {
      bf16x8 pa = *reinterpret_cast<const bf16x8*>(&pw[(g * 16 + r) * 72 + kc * 32 + q4 * 8]);
      #pragma unroll
      for (int d0 = 0; d0 < 4; d0++)
        of[g][d0] = __builtin_amdgcn_mfma_f32_16x16x32_bf16(vf[kc][d0], pa, of[g][d0], 0, 0, 0);
    }
}

__global__ __launch_bounds__(512)
void k_attn(const u16* __restrict__ Q, const u16* __restrict__ Kk,
            const u16* __restrict__ Vt, u16* __restrict__ Y)
{
  __shared__ __align__(16) u16 p_sh[8][32 * 72];   // per-wave [32 q][64 k] P tile

  const int u = threadIdx.x;
  const int lane = u & 63;
  const int w = u >> 6;                 // 0..7
  const int r = lane & 15, q4 = lane >> 4;
  // XCD-resident head map: all 8 blocks of a head share blockIdx&7
  const int xcd = blockIdx.x & 7;
  const int j = blockIdx.x >> 3;        // 0..31
  const int bh = xcd * 4 + (j >> 3);    // 0..31
  const int i = j & 7;                  // block index within head, 0..7
  const int s = w & 3, half = w >> 2;
  const int wt = half ? (63 - (4 * i + s)) : (4 * i + s);   // SIMD s: cheap+expensive pair
  const int b = bh >> 4, h = bh & 15;
  const size_t head_off = (size_t)bh * TT * HD;   // Q,K: [t][d];  Vt: [d][t]
  const int q0 = wt * 32;
  const int lastkt = wt >> 1;

  const u16* Kp = Kk + head_off + (size_t)r * HD + q4 * 8;
  const u16* Vp = Vt + head_off + (size_t)r * TT + q4 * 8;

  bf16x8 qf[2][2];
  #pragma unroll
  for (int g = 0; g < 2; g++) {
    const u16* qp = &Q[head_off + (size_t)(q0 + g * 16 + r) * HD + q4 * 8];
    qf[g][0] = *reinterpret_cast<const bf16x8*>(qp);
    qf[g][1] = *reinterpret_cast<const bf16x8*>(qp + 32);
  }

  f32x4 of[2][4];
  #pragma unroll
  for (int g = 0; g < 2; g++)
    #pragma unroll
    for (int k = 0; k < 4; k++) of[g][k] = {0.f, 0.f, 0.f, 0.f};
  float m_run[2] = {-1e30f, -1e30f};
  float lp[2] = {0.f, 0.f};

  u16* pw = &p_sh[w][0];

  // prologue: load K tile 0 into kfA
  bf16x8 kfA[8], kfB[8];
  #pragma unroll
  for (int n = 0; n < 4; n++) {
    kfA[n * 2 + 0] = *reinterpret_cast<const bf16x8*>(Kp + n * 1024);
    kfA[n * 2 + 1] = *reinterpret_cast<const bf16x8*>(Kp + n * 1024 + 32);
  }

  for (int kt = 0; kt <= lastkt; kt += 2) {
    attn_tile(Kp, Vp, kfA, kfB, qf, of, m_run, lp, pw, kt, kt == lastkt, q0, r, q4);
    if (kt + 1 <= lastkt)
      attn_tile(Kp, Vp, kfB, kfA, qf, of, m_run, lp, pw, kt + 1, kt + 1 == lastkt, q0, r, q4);
  }

  // epilogue: reduce per-lane partial l across q4 lanes, packed bf16 stores
  #pragma unroll
  for (int g = 0; g < 2; g++) {
    float l = lp[g];
    l += __shfl_xor(l, 16);
    l += __shfl_xor(l, 32);
    float inv = 1.0f / l;
    const int t = q0 + g * 16 + r;
    #pragma unroll
    for (int d0 = 0; d0 < 4; d0++) {
      bf16x4v yv;
      yv[0] = (__bf16)(of[g][d0][0] * inv); yv[1] = (__bf16)(of[g][d0][1] * inv);
      yv[2] = (__bf16)(of[g][d0][2] * inv); yv[3] = (__bf16)(of[g][d0][3] * inv);
      *reinterpret_cast<bf16x4v*>(&Y[((size_t)(b * TT + t) << 10) + h * 64 + d0 * 16 + q4 * 4]) = yv;
    }
  }
}

// ---------------- host launcher ----------------
extern "C" void kernel_launch(void* const* d_in, const int* in_sizes, int n_in,
                              void* d_out, int out_size, void* d_ws, size_t ws_size,
                              hipStream_t stream) {
  const float* x     = (const float*)d_in[0];
  const float* w_qkv = (const float*)d_in[1];
  const float* b_qkv = (const float*)d_in[2];
  const float* w_out = (const float*)d_in[3];
  const float* b_out = (const float*)d_in[4];
  float* out = (float*)d_out;

  uint8_t* ws = (uint8_t*)d_ws;
  u16* xb    = (u16*)(ws);                    // 8 MB  (reused as y_heads later)
  u16* wqkvT = (u16*)(ws + (8u  << 20));      // 6 MB
  u16* woutT = (u16*)(ws + (14u << 20));      // 2 MB
  u16* Qh    = (u16*)(ws + (16u << 20));      // 8 MB
  u16* Kh    = (u16*)(ws + (24u << 20));      // 8 MB
  u16* Vth   = (u16*)(ws + (32u << 20));      // 8 MB  (transposed V; also absorbs K prefetch overfetch)

  k_f32_to_bf16<<<1024, 256, 0, stream>>>(x, xb, (MR * D_MODEL) / 4);
  k_transpose_both<<<dim3(128, D_MODEL / 32), dim3(32, 8), 0, stream>>>(
      w_qkv, w_out, wqkvT, woutT);

  k_gemm_bt<0><<<dim3(3 * D_MODEL / 64, MR / 128), 256, 0, stream>>>(
      xb, wqkvT, b_qkv, Qh, Kh, Vth, nullptr, MR, 3 * D_MODEL, D_MODEL);

  u16* Yh = xb;  // reuse x-bf16 region
  k_attn<<<dim3(256), dim3(512), 0, stream>>>(Qh, Kh, Vth, Yh);

  k_gemm_bt<1><<<dim3(D_MODEL / 64, MR / 128), 256, 0, stream>>>(
      Yh, woutT, b_out, nullptr, nullptr, nullptr, out, MR, D_MODEL, D_MODEL);
}